// Round 2
// baseline (160.366 us; speedup 1.0000x reference)
//
#include <hip/hip_runtime.h>
#include <cstdint>
#include <cstddef>

// GAT layer: B=4, H=8, N=2048, Din=256, O=64
// out[b,h,i,o] = sum_j softmax_j(leaky_relu(src[i]+dst[j])) * h_[b,h,j,o] + bias[o]
//
// Tricks:
//  - row max of logits = leaky(src_i + max_j dst_j) exactly (monotonicity) -> no
//    online rescaling; p <= 1 always. src/dst pre-scaled by log2e -> raw v_exp_f32.
//  - row sum of p computed by MFMA with an all-ones B fragment -> lands in the
//    same lane/reg slot as the PV accumulator row -> shuffle-free normalization.
//  - f32->bf16 by +0x8000 round-half-up + v_perm_b32 pair-pack (1 op/pair).

#define HEADS 8
#define DIN   256
#define HDIM  64
#define NN    2048

typedef __attribute__((ext_vector_type(8))) short bf16x8;
typedef __attribute__((ext_vector_type(4))) float f32x4;

union BF8 { bf16x8 v; unsigned u[4]; };

__device__ __forceinline__ unsigned pkbf(float a, float b) {
  // returns (bf16(b)<<16) | bf16(a), round-half-up
  union { float f; unsigned u; } ua, ub; ua.f = a; ub.f = b;
  return __builtin_amdgcn_perm(ub.u + 0x8000u, ua.u + 0x8000u, 0x07060302u);
}

__device__ __forceinline__ unsigned short f2bf(float f) {
  union { float f; unsigned u; } v; v.f = f;
  unsigned r = v.u + 0x7FFFu + ((v.u >> 16) & 1u);   // RNE
  return (unsigned short)(r >> 16);
}

// ---------------- k0: w [H][K][O] f32 -> wt [H][O][K] bf16 ----------------
__global__ __launch_bounds__(256) void gat_wt(const float* __restrict__ w,
                                              unsigned short* __restrict__ wt) {
  const int idx = blockIdx.x * 256 + threadIdx.x;   // over 8*256*64 = 131072
  const int o  = idx & 63;
  const int k  = (idx >> 6) & 255;
  const int hd = idx >> 14;
  wt[(hd * HDIM + o) * DIN + k] = f2bf(w[idx]);
}

// ---------------- k1: projection + fused src/dst logit vectors ------------
// grid (HEADS, 64): head = bx, 128-row tile of B*N=8192 = by
__global__ __launch_bounds__(256) void gat_proj(const float* __restrict__ h,
                                                const unsigned short* __restrict__ wt,
                                                const float* __restrict__ a_src,
                                                const float* __restrict__ a_dst,
                                                unsigned short* __restrict__ h_t,
                                                float* __restrict__ src_s,
                                                float* __restrict__ dst_s) {
  const int head = blockIdx.x;
  const int rt   = blockIdx.y;
  const int tid  = threadIdx.x;
  const int w    = tid >> 6;
  const int lane = tid & 63;
  const int l15  = lane & 15, lg = lane >> 4;

  const int rowg = rt * 128 + w * 32;                 // global row in [0,8192)
  const float* hb = h + (size_t)rowg * DIN;
  const unsigned short* wb = wt + head * (HDIM * DIN);

  f32x4 acc[2][4] = {};
#pragma unroll
  for (int kk = 0; kk < 8; ++kk) {
    const int k0 = kk * 32 + lg * 8;
    bf16x8 af[2];
#pragma unroll
    for (int m = 0; m < 2; ++m) {
      const float* ap = hb + (size_t)(m * 16 + l15) * DIN + k0;
      float4 x0 = *(const float4*)ap;
      float4 x1 = *(const float4*)(ap + 4);
      BF8 t;
      t.u[0] = pkbf(x0.x, x0.y); t.u[1] = pkbf(x0.z, x0.w);
      t.u[2] = pkbf(x1.x, x1.y); t.u[3] = pkbf(x1.z, x1.w);
      af[m] = t.v;
    }
    bf16x8 bfr[4];
#pragma unroll
    for (int n = 0; n < 4; ++n)
      bfr[n] = *(const bf16x8*)(wb + (size_t)(n * 16 + l15) * DIN + k0);
#pragma unroll
    for (int m = 0; m < 2; ++m)
#pragma unroll
      for (int n = 0; n < 4; ++n)
        acc[m][n] = __builtin_amdgcn_mfma_f32_16x16x32_bf16(af[m], bfr[n], acc[m][n], 0, 0, 0);
  }

  // write transposed: h_t[bh][o][n]; C regs are 4 consecutive rows(n), same col(o)
  const int b   = (rt * 128) >> 11;
  const int nl0 = ((rt * 128) & 2047) + w * 32;       // node index within batch b
  const int bh  = b * HEADS + head;
  unsigned short* hb_t = h_t + (size_t)bh * (HDIM * NN);
#pragma unroll
  for (int m = 0; m < 2; ++m)
#pragma unroll
    for (int n = 0; n < 4; ++n) {
      uint2 pk;
      pk.x = pkbf(acc[m][n][0], acc[m][n][1]);
      pk.y = pkbf(acc[m][n][2], acc[m][n][3]);
      const int o  = n * 16 + l15;
      const int nl = nl0 + m * 16 + lg * 4;
      *(uint2*)(hb_t + (size_t)o * NN + nl) = pk;
    }

  // fused src/dst: src[node] = sum_o h_[node][o]*a_src[o]  (f32 acc, pre-bias)
  const float LOG2E = 1.4426950408889634f;
  float as4[4], ad4[4];
#pragma unroll
  for (int n = 0; n < 4; ++n) {
    as4[n] = a_src[head * HDIM + n * 16 + l15];
    ad4[n] = a_dst[head * HDIM + n * 16 + l15];
  }
#pragma unroll
  for (int m = 0; m < 2; ++m)
#pragma unroll
    for (int reg = 0; reg < 4; ++reg) {
      float ps = 0.f, pd = 0.f;
#pragma unroll
      for (int n = 0; n < 4; ++n) {
        float c = acc[m][n][reg];
        ps = fmaf(c, as4[n], ps);
        pd = fmaf(c, ad4[n], pd);
      }
#pragma unroll
      for (int off = 1; off <= 8; off <<= 1) {
        ps += __shfl_xor(ps, off);
        pd += __shfl_xor(pd, off);
      }
      if (l15 == 0) {
        const int nl = nl0 + m * 16 + lg * 4 + reg;
        src_s[(size_t)bh * NN + nl] = ps * LOG2E;
        dst_s[(size_t)bh * NN + nl] = pd * LOG2E;
      }
    }
}

// ---------------- k3: flash GAT attention ---------------------------------
// grid (32, 32): i-tile(64 rows) = bx, bh = by; 4 waves x 16 rows each
__global__ __launch_bounds__(256) void gat_flash(const float* __restrict__ src_s,
                                                 const float* __restrict__ dst_s,
                                                 const unsigned short* __restrict__ h_t,
                                                 const float* __restrict__ bias,
                                                 float* __restrict__ out) {
  const int it  = blockIdx.x;
  const int bh  = blockIdx.y;
  const int tid = threadIdx.x;
  const int w   = tid >> 6;
  const int lane = tid & 63;
  const int l15 = lane & 15, lg = lane >> 4;

  const float* dstp = dst_s + (size_t)bh * NN;

  // exact global max of dst for this (b,h)
  float dm = -1e30f;
#pragma unroll
  for (int t = 0; t < NN / 256; ++t) dm = fmaxf(dm, dstp[tid + t * 256]);
#pragma unroll
  for (int off = 32; off >= 1; off >>= 1) dm = fmaxf(dm, __shfl_xor(dm, off));
  __shared__ float red[4];
  if (lane == 0) red[w] = dm;
  __syncthreads();
  dm = fmaxf(fmaxf(red[0], red[1]), fmaxf(red[2], red[3]));

  // this lane's A-frag row = l15 of the wave's 16-row tile
  const float sv   = src_s[(size_t)bh * NN + it * 64 + w * 16 + l15];
  const float smax = sv + dm;
  const float mi   = fmaxf(smax, 0.2f * smax);   // exact row max (log2 domain)
  const float sm0  = sv - mi;                    // pos branch:  p2 = sm0 + d
  const float c0   = fmaf(0.2f, sv, -mi);        // neg branch:  p2 = 0.2*d + c0

  f32x4 acc[4] = {};
  f32x4 accs   = {};
  BF8 onesU; onesU.u[0] = onesU.u[1] = onesU.u[2] = onesU.u[3] = 0x3F803F80u;
  const bf16x8 ones = onesU.v;
  const unsigned short* vb = h_t + (size_t)bh * (HDIM * NN);

  for (int jc = 0; jc < NN / 32; ++jc) {
    const int k0 = jc * 32 + lg * 8;
    float4 d0 = *(const float4*)(dstp + k0);
    float4 d1 = *(const float4*)(dstp + k0 + 4);
    const float dv[8] = {d0.x, d0.y, d0.z, d0.w, d1.x, d1.y, d1.z, d1.w};

    float p[8];
#pragma unroll
    for (int jj = 0; jj < 8; ++jj) {
      float a  = sm0 + dv[jj];
      float b2 = fmaf(0.2f, dv[jj], c0);
      p[jj] = __builtin_amdgcn_exp2f(fmaxf(a, b2));   // <= 1 always
    }
    BF8 afu;
    afu.u[0] = pkbf(p[0], p[1]); afu.u[1] = pkbf(p[2], p[3]);
    afu.u[2] = pkbf(p[4], p[5]); afu.u[3] = pkbf(p[6], p[7]);
    const bf16x8 af = afu.v;

    bf16x8 bfr[4];
#pragma unroll
    for (int n = 0; n < 4; ++n)
      bfr[n] = *(const bf16x8*)(vb + (size_t)(n * 16 + l15) * NN + k0);
#pragma unroll
    for (int n = 0; n < 4; ++n)
      acc[n] = __builtin_amdgcn_mfma_f32_16x16x32_bf16(af, bfr[n], acc[n], 0, 0, 0);
    accs = __builtin_amdgcn_mfma_f32_16x16x32_bf16(af, ones, accs, 0, 0, 0);
  }

  float bb[4];
#pragma unroll
  for (int n = 0; n < 4; ++n) bb[n] = bias[n * 16 + l15];

  float* ob = out + ((size_t)bh * NN + it * 64 + w * 16) * HDIM;
#pragma unroll
  for (int reg = 0; reg < 4; ++reg) {
    const float linv = 1.0f / accs[reg];   // rowsum for row lg*4+reg, same lane
    const int r = lg * 4 + reg;
#pragma unroll
    for (int n = 0; n < 4; ++n)
      ob[(size_t)r * HDIM + n * 16 + l15] = fmaf(acc[n][reg], linv, bb[n]);
  }
}

extern "C" void kernel_launch(void* const* d_in, const int* in_sizes, int n_in,
                              void* d_out, int out_size, void* d_ws, size_t ws_size,
                              hipStream_t stream) {
  const float* h     = (const float*)d_in[0];   // [4,2048,256]
  const float* w     = (const float*)d_in[1];   // [8,256,64]
  const float* a_src = (const float*)d_in[2];   // [8,64,1]
  const float* a_dst = (const float*)d_in[3];   // [8,64,1]
  const float* bias  = (const float*)d_in[4];   // [64]
  float* out = (float*)d_out;                   // [4,8,2048,64]

  // ws layout (~8.75 MB)
  char* ws = (char*)d_ws;
  unsigned short* wt  = (unsigned short*)ws;                       // 256 KB
  unsigned short* h_t = (unsigned short*)(ws + 262144);            // 8 MB (V^T bf16)
  float* src_s = (float*)(ws + 262144 + 8388608);                  // 256 KB
  float* dst_s = (float*)(ws + 262144 + 8388608 + 262144);         // 256 KB

  hipLaunchKernelGGL(gat_wt,    dim3(512),    dim3(256), 0, stream, w, wt);
  hipLaunchKernelGGL(gat_proj,  dim3(8, 64),  dim3(256), 0, stream,
                     h, wt, a_src, a_dst, h_t, src_s, dst_s);
  hipLaunchKernelGGL(gat_flash, dim3(32, 32), dim3(256), 0, stream,
                     src_s, dst_s, h_t, bias, out);
}

// Round 3
// 70.340 us; speedup vs baseline: 2.2799x; 2.2799x over previous
//
#include <hip/hip_runtime.h>
#include <cstdint>
#include <cstddef>

// GAT layer: B=4, H=8, N=2048, Din=256, O=64
// out[b,h,i,o] = sum_j softmax_j(leaky_relu(src[i]+dst[j])) * h_[b,h,j,o] + bias[o]
//
// Tricks:
//  - row max of logits = leaky(src_i + max_j dst_j) exactly (monotonicity) -> no
//    online rescaling; p <= 1 always. src/dst pre-scaled by log2e -> raw v_exp_f32.
//  - p row-sums via MFMA against an all-ones B fragment -> same lane/reg slot as
//    the PV accumulator row -> shuffle-free normalization.
//  - f32->bf16: +0x8000 round-half-up + v_perm_b32 pair pack (3 ops / 2 values).
//  - V stored FRAGMENT-MAJOR: v2[bh][j>>3][o][j&7] so each B-frag load is 4
//    contiguous 256B runs (vs 16-line strided gather from a row-major V^T).
//  - explicit 2-deep register double-buffer of B-frags + dst in flash.

#define HEADS 8
#define DIN   256
#define HDIM  64
#define NN    2048

typedef __attribute__((ext_vector_type(8))) short bf16x8;
typedef __attribute__((ext_vector_type(4))) float f32x4;

union BF8 { bf16x8 v; unsigned u[4]; };

__device__ __forceinline__ unsigned pkbf(float a, float b) {
  // returns (bf16(b)<<16) | bf16(a), round-half-up
  union { float f; unsigned u; } ua, ub; ua.f = a; ub.f = b;
  return __builtin_amdgcn_perm(ub.u + 0x8000u, ua.u + 0x8000u, 0x07060302u);
}

__device__ __forceinline__ unsigned short f2bf(float f) {
  union { float f; unsigned u; } v; v.f = f;
  unsigned r = v.u + 0x7FFFu + ((v.u >> 16) & 1u);   // RNE
  return (unsigned short)(r >> 16);
}

// ---------------- k0: w [H][K][O] f32 -> wt [H][O][K] bf16 ----------------
__global__ __launch_bounds__(256) void gat_wt(const float* __restrict__ w,
                                              unsigned short* __restrict__ wt) {
  const int idx = blockIdx.x * 256 + threadIdx.x;   // over 8*256*64 = 131072
  const int o  = idx & 63;
  const int k  = (idx >> 6) & 255;
  const int hd = idx >> 14;
  wt[(hd * HDIM + o) * DIN + k] = f2bf(w[idx]);
}

// ---------------- k1: projection + fused src/dst logit vectors ------------
// grid (HEADS, 64): head = bx, 128-row tile of B*N=8192 = by
// writes V fragment-major: h_t[bh][g = j>>3][o][j&7]  (g stride 512 elems)
__global__ __launch_bounds__(256) void gat_proj(const float* __restrict__ h,
                                                const unsigned short* __restrict__ wt,
                                                const float* __restrict__ a_src,
                                                const float* __restrict__ a_dst,
                                                unsigned short* __restrict__ h_t,
                                                float* __restrict__ src_s,
                                                float* __restrict__ dst_s) {
  const int head = blockIdx.x;
  const int rt   = blockIdx.y;
  const int tid  = threadIdx.x;
  const int w    = tid >> 6;
  const int lane = tid & 63;
  const int l15  = lane & 15, lg = lane >> 4;

  const int rowg = rt * 128 + w * 32;                 // global row in [0,8192)
  const float* hb = h + (size_t)rowg * DIN;
  const unsigned short* wb = wt + head * (HDIM * DIN);

  f32x4 acc[2][4] = {};
#pragma unroll
  for (int kk = 0; kk < 8; ++kk) {
    const int k0 = kk * 32 + lg * 8;
    bf16x8 af[2];
#pragma unroll
    for (int m = 0; m < 2; ++m) {
      const float* ap = hb + (size_t)(m * 16 + l15) * DIN + k0;
      float4 x0 = *(const float4*)ap;
      float4 x1 = *(const float4*)(ap + 4);
      BF8 t;
      t.u[0] = pkbf(x0.x, x0.y); t.u[1] = pkbf(x0.z, x0.w);
      t.u[2] = pkbf(x1.x, x1.y); t.u[3] = pkbf(x1.z, x1.w);
      af[m] = t.v;
    }
    bf16x8 bfr[4];
#pragma unroll
    for (int n = 0; n < 4; ++n)
      bfr[n] = *(const bf16x8*)(wb + (size_t)(n * 16 + l15) * DIN + k0);
#pragma unroll
    for (int m = 0; m < 2; ++m)
#pragma unroll
      for (int n = 0; n < 4; ++n)
        acc[m][n] = __builtin_amdgcn_mfma_f32_16x16x32_bf16(af[m], bfr[n], acc[m][n], 0, 0, 0);
  }

  // fragment-major store: C regs are 4 consecutive rows(j), same col(o)
  const int b   = (rt * 128) >> 11;
  const int nl0 = ((rt * 128) & 2047) + w * 32;       // node index within batch b
  const int bh  = b * HEADS + head;
  unsigned short* hb_t = h_t + (size_t)bh * (256 * 512);
#pragma unroll
  for (int m = 0; m < 2; ++m)
#pragma unroll
    for (int n = 0; n < 4; ++n) {
      uint2 pk;
      pk.x = pkbf(acc[m][n][0], acc[m][n][1]);
      pk.y = pkbf(acc[m][n][2], acc[m][n][3]);
      const int j0 = nl0 + m * 16 + lg * 4;           // 4 consecutive j
      const int o  = n * 16 + l15;
      *(uint2*)(hb_t + (size_t)(j0 >> 3) * 512 + o * 8 + (j0 & 7)) = pk;
    }

  // fused src/dst: src[node] = sum_o h_[node][o]*a_src[o]  (f32 acc, pre-scaled)
  const float LOG2E = 1.4426950408889634f;
  float as4[4], ad4[4];
#pragma unroll
  for (int n = 0; n < 4; ++n) {
    as4[n] = a_src[head * HDIM + n * 16 + l15];
    ad4[n] = a_dst[head * HDIM + n * 16 + l15];
  }
#pragma unroll
  for (int m = 0; m < 2; ++m)
#pragma unroll
    for (int reg = 0; reg < 4; ++reg) {
      float ps = 0.f, pd = 0.f;
#pragma unroll
      for (int n = 0; n < 4; ++n) {
        float c = acc[m][n][reg];
        ps = fmaf(c, as4[n], ps);
        pd = fmaf(c, ad4[n], pd);
      }
#pragma unroll
      for (int off = 1; off <= 8; off <<= 1) {
        ps += __shfl_xor(ps, off);
        pd += __shfl_xor(pd, off);
      }
      if (l15 == 0) {
        const int nl = nl0 + m * 16 + lg * 4 + reg;
        src_s[(size_t)bh * NN + nl] = ps * LOG2E;
        dst_s[(size_t)bh * NN + nl] = pd * LOG2E;
      }
    }
}

// ---------------- k2: flash GAT attention ---------------------------------
// grid (16, 32): i-tile(128 rows) = bx, bh = by; 4 waves x 32 rows (2 m-tiles)
__global__ __launch_bounds__(256) void gat_flash(const float* __restrict__ src_s,
                                                 const float* __restrict__ dst_s,
                                                 const unsigned short* __restrict__ h_t,
                                                 const float* __restrict__ bias,
                                                 float* __restrict__ out) {
  const int it  = blockIdx.x;
  const int bh  = blockIdx.y;
  const int tid = threadIdx.x;
  const int w   = tid >> 6;
  const int lane = tid & 63;
  const int l15 = lane & 15, lg = lane >> 4;

  const float* dstp = dst_s + (size_t)bh * NN;

  // exact global max of dst for this (b,h)
  float dm = -1e30f;
#pragma unroll
  for (int t = 0; t < NN / 256; ++t) dm = fmaxf(dm, dstp[tid + t * 256]);
#pragma unroll
  for (int off = 32; off >= 1; off >>= 1) dm = fmaxf(dm, __shfl_xor(dm, off));
  __shared__ float red[4];
  if (lane == 0) red[w] = dm;
  __syncthreads();
  dm = fmaxf(fmaxf(red[0], red[1]), fmaxf(red[2], red[3]));

  // per-lane row state: A-frag row = l15 within each 16-row m-tile
  const float* srcp = src_s + (size_t)bh * NN + it * 128 + w * 32;
  float sm0[2], c0[2];
#pragma unroll
  for (int m = 0; m < 2; ++m) {
    float sv   = srcp[m * 16 + l15];
    float smax = sv + dm;
    float mi   = fmaxf(smax, 0.2f * smax);   // exact row max (log2 domain)
    sm0[m] = sv - mi;                        // pos branch:  p2 = sm0 + d
    c0[m]  = fmaf(0.2f, sv, -mi);            // neg branch:  p2 = 0.2*d + c0
  }

  f32x4 acc[2][4] = {};
  f32x4 accs[2]   = {};
  BF8 onesU; onesU.u[0] = onesU.u[1] = onesU.u[2] = onesU.u[3] = 0x3F803F80u;
  const bf16x8 ones = onesU.v;

  // fragment-major base for this lane: group (jc*4+lg), col (n*16+l15)
  const unsigned short* fb = h_t + (size_t)bh * (256 * 512) + lg * 512 + l15 * 8;

#define LOADF(P, jc) do {                                              \
    const unsigned short* fp_ = fb + (size_t)(jc) * 2048;              \
    P##0 = *(const bf16x8*)(fp_);                                      \
    P##1 = *(const bf16x8*)(fp_ + 128);                                \
    P##2 = *(const bf16x8*)(fp_ + 256);                                \
    P##3 = *(const bf16x8*)(fp_ + 384);                                \
    P##d0 = *(const float4*)(dstp + (jc) * 32 + lg * 8);               \
    P##d1 = *(const float4*)(dstp + (jc) * 32 + lg * 8 + 4);           \
  } while (0)

#define FLASH_STEP(B0_, B1_, B2_, B3_, D0_, D1_) do {                  \
    const float dv_[8] = {D0_.x, D0_.y, D0_.z, D0_.w,                  \
                          D1_.x, D1_.y, D1_.z, D1_.w};                 \
    float tb_[8];                                                      \
    _Pragma("unroll") for (int jj = 0; jj < 8; ++jj)                   \
      tb_[jj] = 0.2f * dv_[jj];                                        \
    _Pragma("unroll") for (int m = 0; m < 2; ++m) {                    \
      float p_[8];                                                     \
      _Pragma("unroll") for (int jj = 0; jj < 8; ++jj)                 \
        p_[jj] = __builtin_amdgcn_exp2f(                               \
            fmaxf(sm0[m] + dv_[jj], tb_[jj] + c0[m]));                 \
      BF8 afu_;                                                        \
      afu_.u[0] = pkbf(p_[0], p_[1]); afu_.u[1] = pkbf(p_[2], p_[3]);  \
      afu_.u[2] = pkbf(p_[4], p_[5]); afu_.u[3] = pkbf(p_[6], p_[7]);  \
      acc[m][0] = __builtin_amdgcn_mfma_f32_16x16x32_bf16(afu_.v, B0_, acc[m][0], 0, 0, 0); \
      acc[m][1] = __builtin_amdgcn_mfma_f32_16x16x32_bf16(afu_.v, B1_, acc[m][1], 0, 0, 0); \
      acc[m][2] = __builtin_amdgcn_mfma_f32_16x16x32_bf16(afu_.v, B2_, acc[m][2], 0, 0, 0); \
      acc[m][3] = __builtin_amdgcn_mfma_f32_16x16x32_bf16(afu_.v, B3_, acc[m][3], 0, 0, 0); \
      accs[m]   = __builtin_amdgcn_mfma_f32_16x16x32_bf16(afu_.v, ones, accs[m], 0, 0, 0);  \
    }                                                                  \
  } while (0)

  bf16x8 A0, A1, A2, A3, B0, B1, B2, B3;
  float4 Ad0, Ad1, Bd0, Bd1;

  LOADF(A, 0);
#pragma unroll 1
  for (int jc2 = 0; jc2 < 31; ++jc2) {
    LOADF(B, 2 * jc2 + 1);
    FLASH_STEP(A0, A1, A2, A3, Ad0, Ad1);
    LOADF(A, 2 * jc2 + 2);
    FLASH_STEP(B0, B1, B2, B3, Bd0, Bd1);
  }
  LOADF(B, 63);
  FLASH_STEP(A0, A1, A2, A3, Ad0, Ad1);
  FLASH_STEP(B0, B1, B2, B3, Bd0, Bd1);

#undef LOADF
#undef FLASH_STEP

  float bb[4];
#pragma unroll
  for (int n = 0; n < 4; ++n) bb[n] = bias[n * 16 + l15];

  float* ob = out + ((size_t)bh * NN + it * 128 + w * 32) * HDIM;
#pragma unroll
  for (int m = 0; m < 2; ++m)
#pragma unroll
    for (int reg = 0; reg < 4; ++reg) {
      const float linv = 1.0f / accs[m][reg];   // rowsum, same lane & reg as acc
      const int r = m * 16 + lg * 4 + reg;
#pragma unroll
      for (int n = 0; n < 4; ++n)
        ob[(size_t)r * HDIM + n * 16 + l15] = fmaf(acc[m][n][reg], linv, bb[n]);
    }
}

extern "C" void kernel_launch(void* const* d_in, const int* in_sizes, int n_in,
                              void* d_out, int out_size, void* d_ws, size_t ws_size,
                              hipStream_t stream) {
  const float* h     = (const float*)d_in[0];   // [4,2048,256]
  const float* w     = (const float*)d_in[1];   // [8,256,64]
  const float* a_src = (const float*)d_in[2];   // [8,64,1]
  const float* a_dst = (const float*)d_in[3];   // [8,64,1]
  const float* bias  = (const float*)d_in[4];   // [64]
  float* out = (float*)d_out;                   // [4,8,2048,64]

  // ws layout (~8.75 MB)
  char* ws = (char*)d_ws;
  unsigned short* wt  = (unsigned short*)ws;                       // 256 KB
  unsigned short* h_t = (unsigned short*)(ws + 262144);            // 8 MB (V frag-major)
  float* src_s = (float*)(ws + 262144 + 8388608);                  // 256 KB
  float* dst_s = (float*)(ws + 262144 + 8388608 + 262144);         // 256 KB

  hipLaunchKernelGGL(gat_wt,    dim3(512),    dim3(256), 0, stream, w, wt);
  hipLaunchKernelGGL(gat_proj,  dim3(8, 64),  dim3(256), 0, stream,
                     h, wt, a_src, a_dst, h_t, src_s, dst_s);
  hipLaunchKernelGGL(gat_flash, dim3(16, 32), dim3(256), 0, stream,
                     src_s, dst_s, h_t, bias, out);
}